// Round 5
// baseline (89576.984 us; speedup 1.0000x reference)
//
#include <hip/hip_runtime.h>
#include <hip/hip_bf16.h>
#include <cmath>

#define FPS_N 8192
#define FPS_K 4096
#define CS    256
#define NEGINF (-__builtin_inff())
#define KMAX  0x7fffffff
#define FPS_LDS_BYTES 147456   // 8192*16 (float4 x,y,z,dd) + 8192*2 (u16 orig id)

// Minkowski-p3 "sum of |d|^3" with reference-exact f32 op order (no FMA contraction).
__device__ __forceinline__ float p3sum(float x, float y, float z,
                                       float nx, float ny, float nz) {
  float dx = fabsf(__fsub_rn(x, nx));
  float dy = fabsf(__fsub_rn(y, ny));
  float dz = fabsf(__fsub_rn(z, nz));
  float cx = __fmul_rn(__fmul_rn(dx, dx), dx);
  float cy = __fmul_rn(__fmul_rn(dy, dy), dy);
  float cz = __fmul_rn(__fmul_rn(dz, dz), dz);
  return __fadd_rn(__fadd_rn(cx, cy), cz);
}

// Squared Euclidean distance, reference-exact f32 op order.
__device__ __forceinline__ float eucl2(float x, float y, float z,
                                       float nx, float ny, float nz) {
  float dx = __fsub_rn(x, nx);
  float dy = __fsub_rn(y, ny);
  float dz = __fsub_rn(z, nz);
  return __fadd_rn(__fadd_rn(__fmul_rn(dx, dx), __fmul_rn(dy, dy)),
                   __fmul_rn(dz, dz));
}

#define LEXGT(va, ka, vb, kb) (((va) > (vb)) || ((va) == (vb) && ((ka) < (kb))))
#define SELP(va, ka, vb, kb) { bool t_ = LEXGT(vb, kb, va, ka); \
  va = t_ ? (vb) : (va); ka = t_ ? (kb) : (ka); }

// DPP lex-max select: (v,k) with v float desc, k int asc tie-break.
template<int CTRL>
__device__ __forceinline__ void dpp_sel2(float& v, int& k) {
  int nv = __builtin_amdgcn_update_dpp(__float_as_int(v), __float_as_int(v), CTRL, 0xF, 0xF, false);
  int nk = __builtin_amdgcn_update_dpp(k, k, CTRL, 0xF, 0xF, false);
  float fv = __int_as_float(nv);
  bool t = LEXGT(fv, nk, v, k);
  v = t ? fv : v;
  k = t ? nk : k;
}

// ---------------------------------------------------------------------------
// 12-bit Morton (16x16x16 over [-4,4]^3) counting sort -> SoA px/py/pz + u16
// orig ids. Also zeroes the selection-flag byte array and marks orig 0.
// Within-cell order is nondeterministic (atomics); all downstream results are
// invariant to it (lex keys on orig index; conservative bbox gates; min/max
// commutativity).
// ---------------------------------------------------------------------------
__global__ __launch_bounds__(1024) void bin_kernel(const float* __restrict__ pos,
                                                   float* __restrict__ px,
                                                   float* __restrict__ py,
                                                   float* __restrict__ pz,
                                                   unsigned short* __restrict__ ids16,
                                                   unsigned char* __restrict__ selb) {
  __shared__ int hist[4096];
  __shared__ int part[1024];
  const int tid = threadIdx.x;
#pragma unroll
  for (int i = 0; i < 4; ++i) hist[tid * 4 + i] = 0;
  ((int*)selb)[tid * 2 + 0] = 0;
  ((int*)selb)[tid * 2 + 1] = 0;
  if (tid == 0) selb[0] = 1;   // orig index 0 is always selected
  __syncthreads();

  float qx[8], qy[8], qz[8];
  int cell[8];
  {
    const float4* p4 = (const float4*)pos + tid * 6;
    float4 a0 = p4[0], a1 = p4[1], a2 = p4[2], a3 = p4[3], a4 = p4[4], a5 = p4[5];
    qx[0]=a0.x; qy[0]=a0.y; qz[0]=a0.z;
    qx[1]=a0.w; qy[1]=a1.x; qz[1]=a1.y;
    qx[2]=a1.z; qy[2]=a1.w; qz[2]=a2.x;
    qx[3]=a2.y; qy[3]=a2.z; qz[3]=a2.w;
    qx[4]=a3.x; qy[4]=a3.y; qz[4]=a3.z;
    qx[5]=a3.w; qy[5]=a4.x; qz[5]=a4.y;
    qx[6]=a4.z; qy[6]=a4.w; qz[6]=a5.x;
    qx[7]=a5.y; qy[7]=a5.z; qz[7]=a5.w;
  }
#pragma unroll
  for (int j = 0; j < 8; ++j) {
    int ix = min(max((int)floorf((qx[j] + 4.0f) * 2.0f), 0), 15);
    int iy = min(max((int)floorf((qy[j] + 4.0f) * 2.0f), 0), 15);
    int iz = min(max((int)floorf((qz[j] + 4.0f) * 2.0f), 0), 15);
    int m = 0;
#pragma unroll
    for (int b = 0; b < 4; ++b)
      m |= (((ix >> b) & 1) << (3 * b)) | (((iy >> b) & 1) << (3 * b + 1)) |
           (((iz >> b) & 1) << (3 * b + 2));
    cell[j] = m;
    atomicAdd(&hist[m], 1);
  }
  __syncthreads();
  int h0 = hist[tid * 4], h1 = hist[tid * 4 + 1], h2 = hist[tid * 4 + 2], h3 = hist[tid * 4 + 3];
  int s = h0 + h1 + h2 + h3;
  part[tid] = s;
  __syncthreads();
  for (int off = 1; off < 1024; off <<= 1) {
    int u = (tid >= off) ? part[tid - off] : 0;
    __syncthreads();
    part[tid] += u;
    __syncthreads();
  }
  int base = part[tid] - s;
  hist[tid * 4 + 0] = base;
  hist[tid * 4 + 1] = base + h0;
  hist[tid * 4 + 2] = base + h0 + h1;
  hist[tid * 4 + 3] = base + h0 + h1 + h2;
  __syncthreads();
#pragma unroll
  for (int j = 0; j < 8; ++j) {
    int slot = atomicAdd(&hist[cell[j]], 1);
    px[slot] = qx[j];
    py[slot] = qy[j];
    pz[slot] = qz[j];
    ids16[slot] = (unsigned short)(tid * 8 + j);
  }
}

// group scan: refresh exact top-2 of group G (and min-update dd vs winner when
// DOUPD). Reads/writes LDS; per-lane t-order XOR-permuted (bank spread; exact:
// max/min are order-free with distinct lex keys).
#define SCANG(G, DOUPD) { \
  float nv1 = NEGINF, nv2 = NEGINF; int nk1 = KMAX, nk2 = KMAX; \
  const int gbase_ = (lane << 7) + ((G) << 4); \
  _Pragma("unroll") \
  for (int t_ = 0; t_ < 16; ++t_) { \
    const int sidx_ = gbase_ + (t_ ^ (lane & 15)); \
    float4 p_ = lds4[sidx_]; \
    float od_ = p_.w; \
    if (DOUPD) { \
      float nd_ = sqrtf(eucl2(p_.x, p_.y, p_.z, wx, wy, wz)); \
      if (nd_ < od_) { od_ = nd_; ((float*)(lds4 + sidx_))[3] = od_; } \
    } \
    const int key_ = ((int)ldsi[sidx_] << 13) | sidx_; \
    bool b1_ = (od_ > nv1) || (od_ == nv1 && key_ < nk1); \
    bool b2_ = (od_ > nv2) || (od_ == nv2 && key_ < nk2); \
    float ov1_ = nv1; int ok1_ = nk1; \
    nv1 = b1_ ? od_ : nv1;  nk1 = b1_ ? key_ : nk1; \
    nv2 = b1_ ? ov1_ : (b2_ ? od_ : nv2); \
    nk2 = b1_ ? ok1_ : (b2_ ? key_ : nk2); \
  } \
  gmv[G] = nv1; gmk[G] = nk1; gm2v[G] = nv2; gm2k[G] = nk2; }

// ---------------------------------------------------------------------------
// Single-wave FPS. 64 lanes x 128 sorted points (8 groups of 16).
// State: LDS float4 (x,y,z,dd) + u16 orig id; registers: per-group exact
// top-2 (lazy promotion on selection) + group bboxes. No barriers, no LDS
// candidate slots, no ballots. Bit-exact vs reference: dd maintained by the
// reference's own recurrence fminf(dd, sqrtf(eucl2(...))); argmax tie-break =
// lowest orig index via lex keys at every level; bbox gates conservative
// (0.999 margin) so they never change results.
// ---------------------------------------------------------------------------
__global__ __launch_bounds__(64) void fps_kernel(const float* __restrict__ pos,
                                                 const float* __restrict__ spx,
                                                 const float* __restrict__ spy,
                                                 const float* __restrict__ spz,
                                                 const unsigned short* __restrict__ sid,
                                                 unsigned char* __restrict__ selb) {
  extern __shared__ char smem[];
  float4* lds4 = (float4*)smem;                               // 8192 * 16B
  unsigned short* ldsi = (unsigned short*)(smem + 131072);    // 8192 * 2B
  const int lane = threadIdx.x;

  // ---- phase 1: coalesced fill of LDS state + initial dd vs pos[0] ----
  const float p0x = pos[0], p0y = pos[1], p0z = pos[2];
  for (int i = lane; i < FPS_N; i += 64) {
    float X = spx[i], Y = spy[i], Z = spz[i];
    unsigned short oid = sid[i];
    float s = eucl2(X, Y, Z, p0x, p0y, p0z);
    float dd0 = (oid == 0) ? NEGINF : sqrtf(s);
    lds4[i] = make_float4(X, Y, Z, dd0);
    ldsi[i] = oid;
  }
  __asm__ volatile("s_waitcnt lgkmcnt(0)" ::: "memory");
  __builtin_amdgcn_sched_barrier(0);

  // ---- phase 2: per-lane group stats (bbox + exact top-2) ----
  float gmv[8], gm2v[8];
  int   gmk[8], gm2k[8];
  float bnx[8], bny[8], bnz[8], bxx[8], bxy[8], bxz[8];
#pragma unroll
  for (int g = 0; g < 8; ++g) {
    float nv1 = NEGINF, nv2 = NEGINF; int nk1 = KMAX, nk2 = KMAX;
    float mnx = 1e30f, mny = 1e30f, mnz = 1e30f;
    float mxx = -1e30f, mxy = -1e30f, mxz = -1e30f;
    const int gbase = (lane << 7) + (g << 4);
#pragma unroll
    for (int t = 0; t < 16; ++t) {
      const int sidx = gbase + t;
      float4 p = lds4[sidx];
      mnx = fminf(mnx, p.x); mny = fminf(mny, p.y); mnz = fminf(mnz, p.z);
      mxx = fmaxf(mxx, p.x); mxy = fmaxf(mxy, p.y); mxz = fmaxf(mxz, p.z);
      float od = p.w;
      int key = ((int)ldsi[sidx] << 13) | sidx;
      bool b1 = (od > nv1) || (od == nv1 && key < nk1);
      bool b2 = (od > nv2) || (od == nv2 && key < nk2);
      float ov1 = nv1; int ok1 = nk1;
      nv1 = b1 ? od : nv1;  nk1 = b1 ? key : nk1;
      nv2 = b1 ? ov1 : (b2 ? od : nv2);
      nk2 = b1 ? ok1 : (b2 ? key : nk2);
    }
    gmv[g] = nv1; gmk[g] = nk1; gm2v[g] = nv2; gm2k[g] = nk2;
    bnx[g] = mnx; bny[g] = mny; bnz[g] = mnz;
    bxx[g] = mxx; bxy[g] = mxy; bxz[g] = mxz;
  }
  // lane bbox = union of group bboxes
  float lbnx = bnx[0], lbny = bny[0], lbnz = bnz[0];
  float lbxx = bxx[0], lbxy = bxy[0], lbxz = bxz[0];
#pragma unroll
  for (int g = 1; g < 8; ++g) {
    lbnx = fminf(lbnx, bnx[g]); lbny = fminf(lbny, bny[g]); lbnz = fminf(lbnz, bnz[g]);
    lbxx = fmaxf(lbxx, bxx[g]); lbxy = fmaxf(lbxy, bxy[g]); lbxz = fmaxf(lbxz, bxz[g]);
  }

  unsigned long long m0 = 0ull, m1 = 0ull;   // selected bits for my 128 slots

  // ---- main loop: 4095 exact selections, zero barriers ----
  for (int k = 0; k < FPS_K - 1; ++k) {
    // lane candidate: tree tournament over 8 register group-tops
    float v0 = gmv[0], v1 = gmv[1], v2 = gmv[2], v3 = gmv[3];
    float v4 = gmv[4], v5 = gmv[5], v6 = gmv[6], v7 = gmv[7];
    int k0 = gmk[0], k1 = gmk[1], k2 = gmk[2], k3 = gmk[3];
    int k4 = gmk[4], k5 = gmk[5], k6 = gmk[6], k7 = gmk[7];
    SELP(v0, k0, v1, k1) SELP(v2, k2, v3, k3)
    SELP(v4, k4, v5, k5) SELP(v6, k6, v7, k7)
    SELP(v0, k0, v2, k2) SELP(v4, k4, v6, k6)
    SELP(v0, k0, v4, k4)
    const float lcv = v0;

    // wave winner via 6-level DPP lex reduce -> lane 63 -> sgpr
    float rv = v0; int rk = k0;
    dpp_sel2<0x111>(rv, rk); dpp_sel2<0x112>(rv, rk); dpp_sel2<0x114>(rv, rk);
    dpp_sel2<0x118>(rv, rk); dpp_sel2<0x142>(rv, rk); dpp_sel2<0x143>(rv, rk);
    const int wk = __builtin_amdgcn_readlane(rk, 63);
    const int stor = wk & 8191;

    // winner coords (wave-uniform LDS broadcast read)
    float4 wrec = lds4[stor];
    const float wx = wrec.x, wy = wrec.y, wz = wrec.z;

    // owner: mark selected + exact lazy top-2 promotion (rare: full rescan)
    if ((stor >> 7) == lane) {
      ((float*)(lds4 + stor))[3] = NEGINF;
      const int b = stor & 127;
      if (b < 64) m0 |= (1ull << b); else m1 |= (1ull << (b - 64));
      const int gw = (stor >> 4) & 7;
#pragma unroll
      for (int g = 0; g < 8; ++g)
        if (g == gw) {
          if (gm2k[g] != KMAX || gm2v[g] != NEGINF) {
            // top-2 is exact (only the selected top-1 changed since last scan)
            gmv[g] = gm2v[g]; gmk[g] = gm2k[g];
            gm2v[g] = NEGINF; gm2k[g] = KMAX;
          } else {
            SCANG(g, 0)
          }
        }
    }

    // conservative lane-level gate, then per-group gates + update scans
    float cx = fminf(fmaxf(wx, lbnx), lbxx);
    float cy = fminf(fmaxf(wy, lbny), lbxy);
    float cz = fminf(fmaxf(wz, lbnz), lbxz);
    float ddx = wx - cx, ddy = wy - cy, ddz = wz - cz;
    float bd2 = ddx * ddx + ddy * ddy + ddz * ddz;
    float lg = fmaxf(lcv, 0.f);
    if (bd2 * 0.999f < lg * lg) {
#pragma unroll
      for (int g = 0; g < 8; ++g) {
        float gv = fmaxf(gmv[g], 0.f);
        float gcx = fminf(fmaxf(wx, bnx[g]), bxx[g]);
        float gcy = fminf(fmaxf(wy, bny[g]), bxy[g]);
        float gcz = fminf(fmaxf(wz, bnz[g]), bxz[g]);
        float gdx = wx - gcx, gdy = wy - gcy, gdz = wz - gcz;
        float gb2 = gdx * gdx + gdy * gdy + gdz * gdz;
        if (gb2 * 0.999f < gv * gv) { SCANG(g, 1) }
      }
    }
  }

  // ---- emit selection flags to global (orig-indexed) ----
#pragma unroll 4
  for (int j = 0; j < 128; ++j) {
    bool s = (j < 64) ? ((m0 >> j) & 1ull) : ((m1 >> (j - 64)) & 1ull);
    if (s) selb[ldsi[(lane << 7) + j]] = 1;
  }
}

// ---------------------------------------------------------------------------
// Emit selected points in ascending ORIGINAL index order (block prefix sum).
// ---------------------------------------------------------------------------
__global__ __launch_bounds__(1024) void emit_kernel(const unsigned char* __restrict__ selb,
                                                    const float* __restrict__ pos,
                                                    float* __restrict__ pos_out) {
  __shared__ int sc[1024];
  const int tid = threadIdx.x;
  int w0 = ((const int*)selb)[tid * 2 + 0];
  int w1 = ((const int*)selb)[tid * 2 + 1];
  int cnt = __popc(w0) + __popc(w1);    // bytes are exactly 0 or 1
  sc[tid] = cnt;
  __syncthreads();
  for (int off = 1; off < 1024; off <<= 1) {
    int u = (tid >= off) ? sc[tid - off] : 0;
    __syncthreads();
    sc[tid] += u;
    __syncthreads();
  }
  int r = sc[tid] - cnt;
#pragma unroll
  for (int j = 0; j < 8; ++j) {
    int w = (j < 4) ? w0 : w1;
    if ((w >> ((j & 3) * 8)) & 1) {
      int oi = tid * 8 + j;
      pos_out[r * 3 + 0] = pos[oi * 3 + 0];
      pos_out[r * 3 + 1] = pos[oi * 3 + 1];
      pos_out[r * 3 + 2] = pos[oi * 3 + 2];
      ++r;
    }
  }
}

// ---------------------------------------------------------------------------
// W^T (256x256) into scratch (start of mask region; overwritten later).
// ---------------------------------------------------------------------------
__global__ __launch_bounds__(256) void wt_kernel(const float* __restrict__ W,
                                                 float* __restrict__ WT) {
  int i = blockIdx.x * 256 + threadIdx.x;
  int c = i >> 8, cp = i & 255;
  WT[i] = W[cp * 256 + c];
}

// ---------------------------------------------------------------------------
// Fused sparse aggregation + Linear. One block per node m.
// ---------------------------------------------------------------------------
__global__ __launch_bounds__(256) void agg_linear_kernel(
    const float* __restrict__ h, const float* __restrict__ pos,
    const float* __restrict__ nodepos, const float* __restrict__ WT,
    const float* __restrict__ bias, float* __restrict__ embed, float sb) {
  const int m = blockIdx.x;
  const int tid = threadIdx.x;
  const int lane = tid & 63, wave = tid >> 6;
  const float nx = nodepos[m * 3 + 0];
  const float ny = nodepos[m * 3 + 1];
  const float nz = nodepos[m * 3 + 2];
  const float4* h4 = (const float4*)h;

  float4 acc = make_float4(0.f, 0.f, 0.f, 0.f);
  const int base0 = wave * (FPS_N / 4);
  for (int base = base0; base < base0 + (FPS_N / 4); base += 64) {
    int n = base + lane;
    float px = pos[n * 3 + 0], py = pos[n * 3 + 1], pz = pos[n * 3 + 2];
    unsigned long long mb = __ballot((p3sum(px, py, pz, nx, ny, nz) <= sb) ? 1 : 0);
    while (mb) {
      int b = __ffsll(mb) - 1;
      mb &= (mb - 1);
      float4 hv = h4[(size_t)(base + b) * 64 + lane];
      acc.x += hv.x; acc.y += hv.y; acc.z += hv.z; acc.w += hv.w;
    }
  }

  __shared__ float lacc[4][256];
  lacc[wave][lane * 4 + 0] = acc.x;
  lacc[wave][lane * 4 + 1] = acc.y;
  lacc[wave][lane * 4 + 2] = acc.z;
  lacc[wave][lane * 4 + 3] = acc.w;
  __syncthreads();
  __shared__ float aggrow[256];
  float aggv = ((lacc[0][tid] + lacc[1][tid]) + lacc[2][tid]) + lacc[3][tid];
  aggrow[tid] = aggv;
  __syncthreads();

  float o = bias[tid];
#pragma unroll 8
  for (int c = 0; c < 256; ++c)
    o = fmaf(aggrow[c], WT[c * 256 + tid], o);
  embed[(size_t)m * 256 + tid] = o;
}

// ---------------------------------------------------------------------------
// Mask output: mask[n][m] = (sum|d|^3 <= sb) ? 1.0 : 0.0   (8192 x 4096 f32)
// ---------------------------------------------------------------------------
__global__ __launch_bounds__(256) void mask_kernel(const float* __restrict__ pos,
                                                   const float* __restrict__ nodepos,
                                                   float* __restrict__ maskout,
                                                   float sb) {
  int n  = blockIdx.y;
  int m0 = (blockIdx.x * 256 + threadIdx.x) * 4;
  float x = pos[n * 3 + 0], y = pos[n * 3 + 1], z = pos[n * 3 + 2];
  const float4* np4 = (const float4*)(nodepos + (size_t)m0 * 3);
  float4 a = np4[0], bq = np4[1], cq = np4[2];
  float4 r;
  r.x = (p3sum(x, y, z, a.x,  a.y,  a.z)  <= sb) ? 1.0f : 0.0f;
  r.y = (p3sum(x, y, z, a.w,  bq.x, bq.y) <= sb) ? 1.0f : 0.0f;
  r.z = (p3sum(x, y, z, bq.z, bq.w, cq.x) <= sb) ? 1.0f : 0.0f;
  r.w = (p3sum(x, y, z, cq.y, cq.z, cq.w) <= sb) ? 1.0f : 0.0f;
  *(float4*)(maskout + (size_t)n * FPS_K + m0) = r;
}

extern "C" void kernel_launch(void* const* d_in, const int* in_sizes, int n_in,
                              void* d_out, int out_size, void* d_ws, size_t ws_size,
                              hipStream_t stream) {
  (void)in_sizes; (void)n_in; (void)out_size; (void)d_ws; (void)ws_size;
  const float* h   = (const float*)d_in[0];
  const float* pos = (const float*)d_in[1];
  const float* W   = (const float*)d_in[2];
  const float* b   = (const float*)d_in[3];

  float* out     = (float*)d_out;
  float* embed   = out;                                   // 4096*256
  float* pos_out = out + (size_t)FPS_K * CS;              // 4096*3
  float* mask    = pos_out + (size_t)FPS_K * 3;           // 8192*4096
  float* WT      = mask;                                  // scratch (overwritten)
  float* px      = mask + (1 << 21);                      // sorted SoA scratch
  float* py      = px + FPS_N;
  float* pz      = py + FPS_N;
  unsigned short* ids16 = (unsigned short*)(pz + FPS_N);  // 16 KB
  unsigned char*  selb  = ((unsigned char*)ids16) + 2 * FPS_N;  // 8 KB flags

  // Threshold model: ref mask true  <=>  cbrt_f32(s) < 0.3f
  const float  t    = 0.3f;
  const float  ulpv = nextafterf(t, 1.0f) - t;
  const double rmid = (double)t - (double)ulpv * 0.5;
  const double C    = rmid * rmid * rmid;
  float sb = (float)C;
  if (!((double)sb < C)) sb = nextafterf(sb, 0.0f);

  // allow 147 KB dynamic LDS for the single-wave FPS kernel (gfx950: 160 KB/WG)
  hipFuncSetAttribute((const void*)fps_kernel,
                      hipFuncAttributeMaxDynamicSharedMemorySize, FPS_LDS_BYTES);

  hipLaunchKernelGGL(bin_kernel, dim3(1), dim3(1024), 0, stream,
                     pos, px, py, pz, ids16, selb);
  hipLaunchKernelGGL(fps_kernel, dim3(1), dim3(64), FPS_LDS_BYTES, stream,
                     pos, px, py, pz, ids16, selb);
  hipLaunchKernelGGL(emit_kernel, dim3(1), dim3(1024), 0, stream,
                     selb, pos, pos_out);
  hipLaunchKernelGGL(wt_kernel, dim3(256), dim3(256), 0, stream, W, WT);
  hipLaunchKernelGGL(agg_linear_kernel, dim3(FPS_K), dim3(256), 0, stream,
                     h, pos, pos_out, WT, b, embed, sb);
  hipLaunchKernelGGL(mask_kernel, dim3(4, FPS_N), dim3(256), 0, stream,
                     pos, pos_out, mask, sb);
}

// Round 6
// 15593.538 us; speedup vs baseline: 5.7445x; 5.7445x over previous
//
#include <hip/hip_runtime.h>
#include <hip/hip_bf16.h>
#include <cmath>

#define FPS_N 8192
#define FPS_K 4096
#define CS    256
#define FT    512          // FPS threads (8 waves)
#define PPT   16           // points per thread
#define NEGINF (-__builtin_inff())
#define KMAX  0x7fffffff
#define FPS_LDS_BYTES (131072 + 128)   // float4[8192] + parity slots

// Minkowski-p3 "sum of |d|^3" with reference-exact f32 op order (no FMA contraction).
__device__ __forceinline__ float p3sum(float x, float y, float z,
                                       float nx, float ny, float nz) {
  float dx = fabsf(__fsub_rn(x, nx));
  float dy = fabsf(__fsub_rn(y, ny));
  float dz = fabsf(__fsub_rn(z, nz));
  float cx = __fmul_rn(__fmul_rn(dx, dx), dx);
  float cy = __fmul_rn(__fmul_rn(dy, dy), dy);
  float cz = __fmul_rn(__fmul_rn(dz, dz), dz);
  return __fadd_rn(__fadd_rn(cx, cy), cz);
}

// Squared Euclidean distance, reference-exact f32 op order.
__device__ __forceinline__ float eucl2(float x, float y, float z,
                                       float nx, float ny, float nz) {
  float dx = __fsub_rn(x, nx);
  float dy = __fsub_rn(y, ny);
  float dz = __fsub_rn(z, nz);
  return __fadd_rn(__fadd_rn(__fmul_rn(dx, dx), __fmul_rn(dy, dy)),
                   __fmul_rn(dz, dz));
}

#define LEXGT(va, ka, vb, kb) (((va) > (vb)) || ((va) == (vb) && ((ka) < (kb))))
#define SELP(va, ka, vb, kb) { bool t_ = LEXGT(vb, kb, va, ka); \
  va = t_ ? (vb) : (va); ka = t_ ? (kb) : (ka); }

// DPP lex-max select: (v,k) with v float desc, k int asc tie-break.
template<int CTRL>
__device__ __forceinline__ void dpp_sel2(float& v, int& k) {
  int nv = __builtin_amdgcn_update_dpp(__float_as_int(v), __float_as_int(v), CTRL, 0xF, 0xF, false);
  int nk = __builtin_amdgcn_update_dpp(k, k, CTRL, 0xF, 0xF, false);
  float fv = __int_as_float(nv);
  bool t = LEXGT(fv, nk, v, k);
  v = t ? fv : v;
  k = t ? nk : k;
}

// ---------------------------------------------------------------------------
// 12-bit Morton (16x16x16 over [-4,4]^3) counting sort -> SoA px/py/pz + u16
// orig ids. Also zeroes the selection-flag byte array and marks orig 0.
// Within-cell order is nondeterministic (atomics); all downstream results are
// invariant to it (lex keys on orig index; conservative bbox gates).
// ---------------------------------------------------------------------------
__global__ __launch_bounds__(1024) void bin_kernel(const float* __restrict__ pos,
                                                   float* __restrict__ px,
                                                   float* __restrict__ py,
                                                   float* __restrict__ pz,
                                                   unsigned short* __restrict__ ids16,
                                                   unsigned char* __restrict__ selb) {
  __shared__ int hist[4096];
  __shared__ int part[1024];
  const int tid = threadIdx.x;
#pragma unroll
  for (int i = 0; i < 4; ++i) hist[tid * 4 + i] = 0;
  ((int*)selb)[tid * 2 + 0] = 0;
  ((int*)selb)[tid * 2 + 1] = 0;
  if (tid == 0) selb[0] = 1;   // orig index 0 is always selected
  __syncthreads();

  float qx[8], qy[8], qz[8];
  int cell[8];
  {
    const float4* p4 = (const float4*)pos + tid * 6;
    float4 a0 = p4[0], a1 = p4[1], a2 = p4[2], a3 = p4[3], a4 = p4[4], a5 = p4[5];
    qx[0]=a0.x; qy[0]=a0.y; qz[0]=a0.z;
    qx[1]=a0.w; qy[1]=a1.x; qz[1]=a1.y;
    qx[2]=a1.z; qy[2]=a1.w; qz[2]=a2.x;
    qx[3]=a2.y; qy[3]=a2.z; qz[3]=a2.w;
    qx[4]=a3.x; qy[4]=a3.y; qz[4]=a3.z;
    qx[5]=a3.w; qy[5]=a4.x; qz[5]=a4.y;
    qx[6]=a4.z; qy[6]=a4.w; qz[6]=a5.x;
    qx[7]=a5.y; qy[7]=a5.z; qz[7]=a5.w;
  }
#pragma unroll
  for (int j = 0; j < 8; ++j) {
    int ix = min(max((int)floorf((qx[j] + 4.0f) * 2.0f), 0), 15);
    int iy = min(max((int)floorf((qy[j] + 4.0f) * 2.0f), 0), 15);
    int iz = min(max((int)floorf((qz[j] + 4.0f) * 2.0f), 0), 15);
    int m = 0;
#pragma unroll
    for (int b = 0; b < 4; ++b)
      m |= (((ix >> b) & 1) << (3 * b)) | (((iy >> b) & 1) << (3 * b + 1)) |
           (((iz >> b) & 1) << (3 * b + 2));
    cell[j] = m;
    atomicAdd(&hist[m], 1);
  }
  __syncthreads();
  int h0 = hist[tid * 4], h1 = hist[tid * 4 + 1], h2 = hist[tid * 4 + 2], h3 = hist[tid * 4 + 3];
  int s = h0 + h1 + h2 + h3;
  part[tid] = s;
  __syncthreads();
  for (int off = 1; off < 1024; off <<= 1) {
    int u = (tid >= off) ? part[tid - off] : 0;
    __syncthreads();
    part[tid] += u;
    __syncthreads();
  }
  int base = part[tid] - s;
  hist[tid * 4 + 0] = base;
  hist[tid * 4 + 1] = base + h0;
  hist[tid * 4 + 2] = base + h0 + h1;
  hist[tid * 4 + 3] = base + h0 + h1 + h2;
  __syncthreads();
#pragma unroll
  for (int j = 0; j < 8; ++j) {
    int slot = atomicAdd(&hist[cell[j]], 1);
    px[slot] = qx[j];
    py[slot] = qy[j];
    pz[slot] = qz[j];
    ids16[slot] = (unsigned short)(tid * 8 + j);
  }
}

// thread-local lex-max over the 16 owned (dd, key) pairs
#define RESCAN() { \
  float v0 = dd[0], v1 = dd[1], v2 = dd[2], v3 = dd[3]; \
  float v4 = dd[4], v5 = dd[5], v6 = dd[6], v7 = dd[7]; \
  float v8 = dd[8], v9 = dd[9], vA = dd[10], vB = dd[11]; \
  float vC = dd[12], vD = dd[13], vE = dd[14], vF = dd[15]; \
  int j0 = key[0], j1 = key[1], j2 = key[2], j3 = key[3]; \
  int j4 = key[4], j5 = key[5], j6 = key[6], j7 = key[7]; \
  int j8 = key[8], j9 = key[9], jA = key[10], jB = key[11]; \
  int jC = key[12], jD = key[13], jE = key[14], jF = key[15]; \
  SELP(v0, j0, v1, j1) SELP(v2, j2, v3, j3) SELP(v4, j4, v5, j5) SELP(v6, j6, v7, j7) \
  SELP(v8, j8, v9, j9) SELP(vA, jA, vB, jB) SELP(vC, jC, vD, jD) SELP(vE, jE, vF, jF) \
  SELP(v0, j0, v2, j2) SELP(v4, j4, v6, j6) SELP(v8, j8, vA, jA) SELP(vC, jC, vE, jE) \
  SELP(v0, j0, v4, j4) SELP(v8, j8, vC, jC) SELP(v0, j0, v8, j8) \
  bv = v0; bkey = j0; }

// ---------------------------------------------------------------------------
// FPS: 512 threads (8 waves) x 16 Morton-sorted points. dd + lex keys + top-1
// cache + bboxes in REGISTERS (full ILP, no LDS RMW chains); coords in
// XOR-swizzled LDS (winner coords = one uniform broadcast read). One barrier
// per iteration (parity candidate slots). Bit-exact vs reference: dd follows
// the reference recurrence fmin(dd, sqrtf(eucl2)); argmax tie-break = lowest
// original index via lex keys; bbox gates conservative (0.999 margin).
// ---------------------------------------------------------------------------
__global__ __launch_bounds__(FT) void fps_kernel(const float* __restrict__ pos,
                                                 const float* __restrict__ spx,
                                                 const float* __restrict__ spy,
                                                 const float* __restrict__ spz,
                                                 const unsigned short* __restrict__ sid,
                                                 unsigned char* __restrict__ selb) {
  extern __shared__ char smem[];
  float4* lds4 = (float4*)smem;                       // 8192 * 16B (xyz + pad)
  int2*   slots = (int2*)(smem + 131072);             // [parity][8 waves]
  const int tid = threadIdx.x, lane = tid & 63, wave = tid >> 6;
  const int xb = tid & 15;                            // swizzle key

  // ---- fill LDS coords (coalesced, swizzled phys = i ^ ((i>>4)&15)) ----
  for (int i = tid; i < FPS_N; i += FT) {
    int ph = i ^ ((i >> 4) & 15);
    lds4[ph] = make_float4(spx[i], spy[i], spz[i], 0.f);
  }
  __syncthreads();

  // ---- per-lane state: dd, keys, boxes ----
  float dd[PPT];
  int   key[PPT];
  const float p0x = pos[0], p0y = pos[1], p0z = pos[2];
  {
    const int4* i4 = (const int4*)sid + tid * 2;   // 16 u16 ids
    int4 b0 = i4[0], b1 = i4[1];
    int op[8] = { b0.x, b0.y, b0.z, b0.w, b1.x, b1.y, b1.z, b1.w };
#pragma unroll
    for (int j = 0; j < PPT; ++j) {
      int oid = (j & 1) ? ((op[j >> 1] >> 16) & 0xffff) : (op[j >> 1] & 0xffff);
      key[j] = (oid << 13) | (tid * PPT + j);
      float4 p = lds4[tid * PPT + (j ^ xb)];
      float s = eucl2(p.x, p.y, p.z, p0x, p0y, p0z);
      dd[j] = (oid == 0) ? NEGINF : sqrtf(s);
    }
  }
  // sub-bboxes (2 x 8 pts) + main bbox
  float s0nx, s0ny, s0nz, s0xx, s0xy, s0xz;
  float s1nx, s1ny, s1nz, s1xx, s1xy, s1xz;
  {
    float4 p = lds4[tid * PPT + (0 ^ xb)];
    s0nx = s0xx = p.x; s0ny = s0xy = p.y; s0nz = s0xz = p.z;
#pragma unroll
    for (int j = 1; j < 8; ++j) {
      float4 q = lds4[tid * PPT + (j ^ xb)];
      s0nx = fminf(s0nx, q.x); s0ny = fminf(s0ny, q.y); s0nz = fminf(s0nz, q.z);
      s0xx = fmaxf(s0xx, q.x); s0xy = fmaxf(s0xy, q.y); s0xz = fmaxf(s0xz, q.z);
    }
    float4 r = lds4[tid * PPT + (8 ^ xb)];
    s1nx = s1xx = r.x; s1ny = s1xy = r.y; s1nz = s1xz = r.z;
#pragma unroll
    for (int j = 9; j < 16; ++j) {
      float4 q = lds4[tid * PPT + (j ^ xb)];
      s1nx = fminf(s1nx, q.x); s1ny = fminf(s1ny, q.y); s1nz = fminf(s1nz, q.z);
      s1xx = fmaxf(s1xx, q.x); s1xy = fmaxf(s1xy, q.y); s1xz = fmaxf(s1xz, q.z);
    }
  }
  const float mnx = fminf(s0nx, s1nx), mny = fminf(s0ny, s1ny), mnz = fminf(s0nz, s1nz);
  const float mxx = fmaxf(s0xx, s1xx), mxy = fmaxf(s0xy, s1xy), mxz = fmaxf(s0xz, s1xz);

  unsigned selmask = 0;
  float bv; int bkey; bool chb = false;
  RESCAN();
  {
    float rv = bv; int rk = bkey;
    dpp_sel2<0x111>(rv, rk); dpp_sel2<0x112>(rv, rk); dpp_sel2<0x114>(rv, rk);
    dpp_sel2<0x118>(rv, rk); dpp_sel2<0x142>(rv, rk); dpp_sel2<0x143>(rv, rk);
    if (lane == 63) slots[wave] = make_int2(__float_as_int(rv), rk);
  }
  __syncthreads();

  for (int k = 0; k < FPS_K - 1; ++k) {
    const int p = k & 1, pn = p ^ 1;
    // ---- global winner: 8 slots, 3 DPP levels, all lanes ----
    int2 sl = slots[p * 8 + (lane & 7)];
    float gv = __int_as_float(sl.x);
    int   gk = sl.y;
    const float kv = gv; const int kk = gk;   // keeper copy (lane==wave)
    dpp_sel2<0xB1>(gv, gk);    // quad_perm [1,0,3,2]
    dpp_sel2<0x4E>(gv, gk);    // quad_perm [2,3,0,1]
    dpp_sel2<0x124>(gv, gk);   // row_ror:4
    const int stor = gk & 8191;

    // ---- winner coords: uniform broadcast read ----
    float4 wrec = lds4[stor ^ ((stor >> 4) & 15)];
    const float wx = wrec.x, wy = wrec.y, wz = wrec.z;

    // ---- owner marks selected ----
    if ((stor >> 4) == tid) {
      const int jj = stor & 15;
      if (jj < 8) {
#pragma unroll
        for (int j = 0; j < 8; ++j) if (j == jj) dd[j] = NEGINF;
      } else {
#pragma unroll
        for (int j = 8; j < 16; ++j) if (j == jj) dd[j] = NEGINF;
      }
      selmask |= (1u << jj);
      chb = true;
    }

    // ---- conservative gated update (reference-exact recurrence) ----
    float lg = fmaxf(bv, 0.f);
    float lg2 = lg * lg;
    float cx = fminf(fmaxf(wx, mnx), mxx);
    float cy = fminf(fmaxf(wy, mny), mxy);
    float cz = fminf(fmaxf(wz, mnz), mxz);
    float ddx = wx - cx, ddy = wy - cy, ddz = wz - cz;
    float bd2 = ddx * ddx + ddy * ddy + ddz * ddz;
    if (bd2 * 0.999f < lg2) {
      {
        float ax = fminf(fmaxf(wx, s0nx), s0xx);
        float ay = fminf(fmaxf(wy, s0ny), s0xy);
        float az = fminf(fmaxf(wz, s0nz), s0xz);
        float ux = wx - ax, uy = wy - ay, uz = wz - az;
        float g2 = ux * ux + uy * uy + uz * uz;
        if (g2 * 0.999f < lg2) {
#pragma unroll
          for (int j = 0; j < 8; ++j) {
            float4 q = lds4[tid * PPT + (j ^ xb)];
            float s = eucl2(q.x, q.y, q.z, wx, wy, wz);
            float nd = sqrtf(s);
            if (nd < dd[j]) { dd[j] = nd; if (key[j] == bkey) chb = true; }
          }
        }
      }
      {
        float ax = fminf(fmaxf(wx, s1nx), s1xx);
        float ay = fminf(fmaxf(wy, s1ny), s1xy);
        float az = fminf(fmaxf(wz, s1nz), s1xz);
        float ux = wx - ax, uy = wy - ay, uz = wz - az;
        float g2 = ux * ux + uy * uy + uz * uz;
        if (g2 * 0.999f < lg2) {
#pragma unroll
          for (int j = 8; j < 16; ++j) {
            float4 q = lds4[tid * PPT + (j ^ xb)];
            float s = eucl2(q.x, q.y, q.z, wx, wy, wz);
            float nd = sqrtf(s);
            if (nd < dd[j]) { dd[j] = nd; if (key[j] == bkey) chb = true; }
          }
        }
      }
    }

    // ---- candidate refresh + parity publish ----
    unsigned long long any = __ballot(chb ? 1 : 0);
    if (any) {
      if (chb) { RESCAN(); chb = false; }
      float rv = bv; int rk = bkey;
      dpp_sel2<0x111>(rv, rk); dpp_sel2<0x112>(rv, rk); dpp_sel2<0x114>(rv, rk);
      dpp_sel2<0x118>(rv, rk); dpp_sel2<0x142>(rv, rk); dpp_sel2<0x143>(rv, rk);
      if (lane == 63) slots[pn * 8 + wave] = make_int2(__float_as_int(rv), rk);
    } else {
      if (lane == wave) slots[pn * 8 + wave] = make_int2(__float_as_int(kv), kk);
    }
    __syncthreads();
  }

  // ---- emit selection flags to global (orig-indexed) ----
#pragma unroll
  for (int j = 0; j < PPT; ++j)
    if ((selmask >> j) & 1) selb[key[j] >> 13] = 1;
}

// ---------------------------------------------------------------------------
// Emit selected points in ascending ORIGINAL index order (block prefix sum).
// ---------------------------------------------------------------------------
__global__ __launch_bounds__(1024) void emit_kernel(const unsigned char* __restrict__ selb,
                                                    const float* __restrict__ pos,
                                                    float* __restrict__ pos_out) {
  __shared__ int sc[1024];
  const int tid = threadIdx.x;
  int w0 = ((const int*)selb)[tid * 2 + 0];
  int w1 = ((const int*)selb)[tid * 2 + 1];
  int cnt = __popc(w0) + __popc(w1);    // bytes are exactly 0 or 1
  sc[tid] = cnt;
  __syncthreads();
  for (int off = 1; off < 1024; off <<= 1) {
    int u = (tid >= off) ? sc[tid - off] : 0;
    __syncthreads();
    sc[tid] += u;
    __syncthreads();
  }
  int r = sc[tid] - cnt;
#pragma unroll
  for (int j = 0; j < 8; ++j) {
    int w = (j < 4) ? w0 : w1;
    if ((w >> ((j & 3) * 8)) & 1) {
      int oi = tid * 8 + j;
      pos_out[r * 3 + 0] = pos[oi * 3 + 0];
      pos_out[r * 3 + 1] = pos[oi * 3 + 1];
      pos_out[r * 3 + 2] = pos[oi * 3 + 2];
      ++r;
    }
  }
}

// ---------------------------------------------------------------------------
// W^T (256x256) into scratch (start of mask region; overwritten later).
// ---------------------------------------------------------------------------
__global__ __launch_bounds__(256) void wt_kernel(const float* __restrict__ W,
                                                 float* __restrict__ WT) {
  int i = blockIdx.x * 256 + threadIdx.x;
  int c = i >> 8, cp = i & 255;
  WT[i] = W[cp * 256 + c];
}

// ---------------------------------------------------------------------------
// Fused sparse aggregation + Linear. One block per node m.
// ---------------------------------------------------------------------------
__global__ __launch_bounds__(256) void agg_linear_kernel(
    const float* __restrict__ h, const float* __restrict__ pos,
    const float* __restrict__ nodepos, const float* __restrict__ WT,
    const float* __restrict__ bias, float* __restrict__ embed, float sb) {
  const int m = blockIdx.x;
  const int tid = threadIdx.x;
  const int lane = tid & 63, wave = tid >> 6;
  const float nx = nodepos[m * 3 + 0];
  const float ny = nodepos[m * 3 + 1];
  const float nz = nodepos[m * 3 + 2];
  const float4* h4 = (const float4*)h;

  float4 acc = make_float4(0.f, 0.f, 0.f, 0.f);
  const int base0 = wave * (FPS_N / 4);
  for (int base = base0; base < base0 + (FPS_N / 4); base += 64) {
    int n = base + lane;
    float px = pos[n * 3 + 0], py = pos[n * 3 + 1], pz = pos[n * 3 + 2];
    unsigned long long mb = __ballot((p3sum(px, py, pz, nx, ny, nz) <= sb) ? 1 : 0);
    while (mb) {
      int b = __ffsll(mb) - 1;
      mb &= (mb - 1);
      float4 hv = h4[(size_t)(base + b) * 64 + lane];
      acc.x += hv.x; acc.y += hv.y; acc.z += hv.z; acc.w += hv.w;
    }
  }

  __shared__ float lacc[4][256];
  lacc[wave][lane * 4 + 0] = acc.x;
  lacc[wave][lane * 4 + 1] = acc.y;
  lacc[wave][lane * 4 + 2] = acc.z;
  lacc[wave][lane * 4 + 3] = acc.w;
  __syncthreads();
  __shared__ float aggrow[256];
  float aggv = ((lacc[0][tid] + lacc[1][tid]) + lacc[2][tid]) + lacc[3][tid];
  aggrow[tid] = aggv;
  __syncthreads();

  float o = bias[tid];
#pragma unroll 8
  for (int c = 0; c < 256; ++c)
    o = fmaf(aggrow[c], WT[c * 256 + tid], o);
  embed[(size_t)m * 256 + tid] = o;
}

// ---------------------------------------------------------------------------
// Mask output: mask[n][m] = (sum|d|^3 <= sb) ? 1.0 : 0.0   (8192 x 4096 f32)
// ---------------------------------------------------------------------------
__global__ __launch_bounds__(256) void mask_kernel(const float* __restrict__ pos,
                                                   const float* __restrict__ nodepos,
                                                   float* __restrict__ maskout,
                                                   float sb) {
  int n  = blockIdx.y;
  int m0 = (blockIdx.x * 256 + threadIdx.x) * 4;
  float x = pos[n * 3 + 0], y = pos[n * 3 + 1], z = pos[n * 3 + 2];
  const float4* np4 = (const float4*)(nodepos + (size_t)m0 * 3);
  float4 a = np4[0], bq = np4[1], cq = np4[2];
  float4 r;
  r.x = (p3sum(x, y, z, a.x,  a.y,  a.z)  <= sb) ? 1.0f : 0.0f;
  r.y = (p3sum(x, y, z, a.w,  bq.x, bq.y) <= sb) ? 1.0f : 0.0f;
  r.z = (p3sum(x, y, z, bq.z, bq.w, cq.x) <= sb) ? 1.0f : 0.0f;
  r.w = (p3sum(x, y, z, cq.y, cq.z, cq.w) <= sb) ? 1.0f : 0.0f;
  *(float4*)(maskout + (size_t)n * FPS_K + m0) = r;
}

extern "C" void kernel_launch(void* const* d_in, const int* in_sizes, int n_in,
                              void* d_out, int out_size, void* d_ws, size_t ws_size,
                              hipStream_t stream) {
  (void)in_sizes; (void)n_in; (void)out_size; (void)d_ws; (void)ws_size;
  const float* h   = (const float*)d_in[0];
  const float* pos = (const float*)d_in[1];
  const float* W   = (const float*)d_in[2];
  const float* b   = (const float*)d_in[3];

  float* out     = (float*)d_out;
  float* embed   = out;                                   // 4096*256
  float* pos_out = out + (size_t)FPS_K * CS;              // 4096*3
  float* mask    = pos_out + (size_t)FPS_K * 3;           // 8192*4096
  float* WT      = mask;                                  // scratch (overwritten)
  float* px      = mask + (1 << 21);                      // sorted SoA scratch
  float* py      = px + FPS_N;
  float* pz      = py + FPS_N;
  unsigned short* ids16 = (unsigned short*)(pz + FPS_N);
  unsigned char*  selb  = ((unsigned char*)ids16) + 2 * FPS_N;

  // Threshold model: ref mask true  <=>  cbrt_f32(s) < 0.3f
  const float  t    = 0.3f;
  const float  ulpv = nextafterf(t, 1.0f) - t;
  const double rmid = (double)t - (double)ulpv * 0.5;
  const double C    = rmid * rmid * rmid;
  float sb = (float)C;
  if (!((double)sb < C)) sb = nextafterf(sb, 0.0f);

  hipFuncSetAttribute((const void*)fps_kernel,
                      hipFuncAttributeMaxDynamicSharedMemorySize, FPS_LDS_BYTES);

  hipLaunchKernelGGL(bin_kernel, dim3(1), dim3(1024), 0, stream,
                     pos, px, py, pz, ids16, selb);
  hipLaunchKernelGGL(fps_kernel, dim3(1), dim3(FT), FPS_LDS_BYTES, stream,
                     pos, px, py, pz, ids16, selb);
  hipLaunchKernelGGL(emit_kernel, dim3(1), dim3(1024), 0, stream,
                     selb, pos, pos_out);
  hipLaunchKernelGGL(wt_kernel, dim3(256), dim3(256), 0, stream, W, WT);
  hipLaunchKernelGGL(agg_linear_kernel, dim3(FPS_K), dim3(256), 0, stream,
                     h, pos, pos_out, WT, b, embed, sb);
  hipLaunchKernelGGL(mask_kernel, dim3(4, FPS_N), dim3(256), 0, stream,
                     pos, pos_out, mask, sb);
}

// Round 7
// 6913.102 us; speedup vs baseline: 12.9576x; 2.2556x over previous
//
#include <hip/hip_runtime.h>
#include <hip/hip_bf16.h>
#include <cmath>

#define FPS_N 8192
#define FPS_K 4096
#define CS    256
#define FT    1024         // FPS threads (16 waves)
#define PPT   8            // points per thread
#define NEGINF (-__builtin_inff())
#define FPS_LDS_BYTES (131072 + 256)   // float4[8192] coords + int2[2][16] slots

// Minkowski-p3 "sum of |d|^3" with reference-exact f32 op order (no FMA contraction).
__device__ __forceinline__ float p3sum(float x, float y, float z,
                                       float nx, float ny, float nz) {
  float dx = fabsf(__fsub_rn(x, nx));
  float dy = fabsf(__fsub_rn(y, ny));
  float dz = fabsf(__fsub_rn(z, nz));
  float cx = __fmul_rn(__fmul_rn(dx, dx), dx);
  float cy = __fmul_rn(__fmul_rn(dy, dy), dy);
  float cz = __fmul_rn(__fmul_rn(dz, dz), dz);
  return __fadd_rn(__fadd_rn(cx, cy), cz);
}

// Squared Euclidean distance, reference-exact f32 op order.
__device__ __forceinline__ float eucl2(float x, float y, float z,
                                       float nx, float ny, float nz) {
  float dx = __fsub_rn(x, nx);
  float dy = __fsub_rn(y, ny);
  float dz = __fsub_rn(z, nz);
  return __fadd_rn(__fadd_rn(__fmul_rn(dx, dx), __fmul_rn(dy, dy)),
                   __fmul_rn(dz, dz));
}

#define LEXGT(va, ka, vb, kb) (((va) > (vb)) || ((va) == (vb) && ((ka) < (kb))))
#define SELP(va, ka, vb, kb) { bool t_ = LEXGT(vb, kb, va, ka); \
  va = t_ ? (vb) : (va); ka = t_ ? (kb) : (ka); }

// DPP lex-max select: (v,k) with v float desc, k int asc tie-break.
template<int CTRL>
__device__ __forceinline__ void dpp_sel2(float& v, int& k) {
  int nv = __builtin_amdgcn_update_dpp(__float_as_int(v), __float_as_int(v), CTRL, 0xF, 0xF, false);
  int nk = __builtin_amdgcn_update_dpp(k, k, CTRL, 0xF, 0xF, false);
  float fv = __int_as_float(nv);
  bool t = LEXGT(fv, nk, v, k);
  v = t ? fv : v;
  k = t ? nk : k;
}

// ---------------------------------------------------------------------------
// 12-bit Morton (16x16x16 over [-4,4]^3) counting sort -> SoA px/py/pz + u16
// orig ids. Also zeroes the selection-flag byte array and marks orig 0.
// Within-cell order is nondeterministic (atomics); all downstream results are
// invariant to it (lex keys on orig index; conservative bbox gates).
// ---------------------------------------------------------------------------
__global__ __launch_bounds__(1024) void bin_kernel(const float* __restrict__ pos,
                                                   float* __restrict__ px,
                                                   float* __restrict__ py,
                                                   float* __restrict__ pz,
                                                   unsigned short* __restrict__ ids16,
                                                   unsigned char* __restrict__ selb) {
  __shared__ int hist[4096];
  __shared__ int part[1024];
  const int tid = threadIdx.x;
#pragma unroll
  for (int i = 0; i < 4; ++i) hist[tid * 4 + i] = 0;
  ((int*)selb)[tid * 2 + 0] = 0;
  ((int*)selb)[tid * 2 + 1] = 0;
  if (tid == 0) selb[0] = 1;   // orig index 0 is always selected
  __syncthreads();

  float qx[8], qy[8], qz[8];
  int cell[8];
  {
    const float4* p4 = (const float4*)pos + tid * 6;
    float4 a0 = p4[0], a1 = p4[1], a2 = p4[2], a3 = p4[3], a4 = p4[4], a5 = p4[5];
    qx[0]=a0.x; qy[0]=a0.y; qz[0]=a0.z;
    qx[1]=a0.w; qy[1]=a1.x; qz[1]=a1.y;
    qx[2]=a1.z; qy[2]=a1.w; qz[2]=a2.x;
    qx[3]=a2.y; qy[3]=a2.z; qz[3]=a2.w;
    qx[4]=a3.x; qy[4]=a3.y; qz[4]=a3.z;
    qx[5]=a3.w; qy[5]=a4.x; qz[5]=a4.y;
    qx[6]=a4.z; qy[6]=a4.w; qz[6]=a5.x;
    qx[7]=a5.y; qy[7]=a5.z; qz[7]=a5.w;
  }
#pragma unroll
  for (int j = 0; j < 8; ++j) {
    int ix = min(max((int)floorf((qx[j] + 4.0f) * 2.0f), 0), 15);
    int iy = min(max((int)floorf((qy[j] + 4.0f) * 2.0f), 0), 15);
    int iz = min(max((int)floorf((qz[j] + 4.0f) * 2.0f), 0), 15);
    int m = 0;
#pragma unroll
    for (int b = 0; b < 4; ++b)
      m |= (((ix >> b) & 1) << (3 * b)) | (((iy >> b) & 1) << (3 * b + 1)) |
           (((iz >> b) & 1) << (3 * b + 2));
    cell[j] = m;
    atomicAdd(&hist[m], 1);
  }
  __syncthreads();
  int h0 = hist[tid * 4], h1 = hist[tid * 4 + 1], h2 = hist[tid * 4 + 2], h3 = hist[tid * 4 + 3];
  int s = h0 + h1 + h2 + h3;
  part[tid] = s;
  __syncthreads();
  for (int off = 1; off < 1024; off <<= 1) {
    int u = (tid >= off) ? part[tid - off] : 0;
    __syncthreads();
    part[tid] += u;
    __syncthreads();
  }
  int base = part[tid] - s;
  hist[tid * 4 + 0] = base;
  hist[tid * 4 + 1] = base + h0;
  hist[tid * 4 + 2] = base + h0 + h1;
  hist[tid * 4 + 3] = base + h0 + h1 + h2;
  __syncthreads();
#pragma unroll
  for (int j = 0; j < 8; ++j) {
    int slot = atomicAdd(&hist[cell[j]], 1);
    px[slot] = qx[j];
    py[slot] = qy[j];
    pz[slot] = qz[j];
    ids16[slot] = (unsigned short)(tid * 8 + j);
  }
}

// thread-local lex-max over the 8 owned (dd, key) pairs (7 SELPs, 3 levels)
#define RESCAN() { \
  float v0 = dd[0], v1 = dd[1], v2 = dd[2], v3 = dd[3]; \
  float v4 = dd[4], v5 = dd[5], v6 = dd[6], v7 = dd[7]; \
  int j0 = key[0], j1 = key[1], j2 = key[2], j3 = key[3]; \
  int j4 = key[4], j5 = key[5], j6 = key[6], j7 = key[7]; \
  SELP(v0, j0, v1, j1) SELP(v2, j2, v3, j3) SELP(v4, j4, v5, j5) SELP(v6, j6, v7, j7) \
  SELP(v0, j0, v2, j2) SELP(v4, j4, v6, j6) SELP(v0, j0, v4, j4) \
  bv = v0; bkey = j0; }

// ---------------------------------------------------------------------------
// FPS: 1024 threads (16 waves) x 8 Morton-sorted register-resident points.
// Slim per-round path: read 16 (v,key) slots -> 4-level DPP lex merge (all
// lanes) -> winner coords via ONE uniform LDS broadcast read -> conservative
// bbox-gated update (reference recurrence dd=fmin(dd,sqrt(eucl2))) -> only
// hit waves rescan+re-publish (6-level DPP); others carry slots forward with
// a single lane write. One barrier per iteration. Bit-exact vs reference:
// same f32 recurrence, lex tie-break = lowest original index everywhere,
// gates conservative (0.999 margin).
// ---------------------------------------------------------------------------
__global__ __launch_bounds__(FT) void fps_kernel(const float* __restrict__ pos,
                                                 const float* __restrict__ spx,
                                                 const float* __restrict__ spy,
                                                 const float* __restrict__ spz,
                                                 const unsigned short* __restrict__ sid,
                                                 unsigned char* __restrict__ selb) {
  extern __shared__ char smem[];
  float4* lds4 = (float4*)smem;                   // 8192 coords (read-only after init)
  int2*   slots = (int2*)(smem + 131072);         // [parity][16 waves]
  const int tid = threadIdx.x, lane = tid & 63, wave = tid >> 6;

  // ---- coalesced LDS coord mirror ----
  for (int i = tid; i < FPS_N; i += FT)
    lds4[i] = make_float4(spx[i], spy[i], spz[i], 0.f);
  __syncthreads();

  // ---- per-thread register state ----
  float x[PPT], y[PPT], z[PPT], dd[PPT];
  int key[PPT];
  const float p0x = pos[0], p0y = pos[1], p0z = pos[2];
  {
    int4 b0 = ((const int4*)sid)[tid];   // 8 u16 orig ids
    int op[4] = { b0.x, b0.y, b0.z, b0.w };
#pragma unroll
    for (int j = 0; j < PPT; ++j) {
      int oid = (j & 1) ? ((op[j >> 1] >> 16) & 0xffff) : (op[j >> 1] & 0xffff);
      key[j] = (oid << 13) | (tid * PPT + j);
      float4 p = lds4[tid * PPT + j];    // one-time (conflicted) read
      x[j] = p.x; y[j] = p.y; z[j] = p.z;
      float s = eucl2(p.x, p.y, p.z, p0x, p0y, p0z);
      dd[j] = (oid == 0) ? NEGINF : sqrtf(s);
    }
  }
  // thread bbox (tight: 8-pt Morton run)
  float mnx = x[0], mny = y[0], mnz = z[0], mxx = x[0], mxy = y[0], mxz = z[0];
#pragma unroll
  for (int j = 1; j < PPT; ++j) {
    mnx = fminf(mnx, x[j]); mny = fminf(mny, y[j]); mnz = fminf(mnz, z[j]);
    mxx = fmaxf(mxx, x[j]); mxy = fmaxf(mxy, y[j]); mxz = fmaxf(mxz, z[j]);
  }

  unsigned selmask = 0;
  float bv; int bkey;
  RESCAN();
  {
    float rv = bv; int rk = bkey;
    dpp_sel2<0x111>(rv, rk); dpp_sel2<0x112>(rv, rk); dpp_sel2<0x114>(rv, rk);
    dpp_sel2<0x118>(rv, rk); dpp_sel2<0x142>(rv, rk); dpp_sel2<0x143>(rv, rk);
    if (lane == 63) slots[wave] = make_int2(__float_as_int(rv), rk);
  }
  __syncthreads();

  for (int k = 0; k < FPS_K - 1; ++k) {
    const int p = k & 1, pn = p ^ 1;
    // ---- global winner: 16 slots, 4 DPP levels, all lanes converge ----
    const int2 sl = slots[p * 16 + (lane & 15)];
    float gv = __int_as_float(sl.x);
    int   gk = sl.y;
    dpp_sel2<0xB1>(gv, gk);    // quad_perm [1,0,3,2]
    dpp_sel2<0x4E>(gv, gk);    // quad_perm [2,3,0,1]
    dpp_sel2<0x124>(gv, gk);   // row_ror:4
    dpp_sel2<0x128>(gv, gk);   // row_ror:8
    const int stor = gk & 8191;

    // ---- winner coords: one uniform broadcast read ----
    const float4 wrec = lds4[stor];
    const float wx = wrec.x, wy = wrec.y, wz = wrec.z;

    // ---- owner marks selected ----
    bool own = false;
    if ((stor >> 3) == tid) {
      const int jj = stor & 7;
#pragma unroll
      for (int j = 0; j < PPT; ++j) if (j == jj) dd[j] = NEGINF;
      selmask |= (1u << jj);
      own = true;
    }

    // ---- conservative bbox gate + reference-exact update ----
    const float lg = fmaxf(bv, 0.f);
    float cx = fminf(fmaxf(wx, mnx), mxx);
    float cy = fminf(fmaxf(wy, mny), mxy);
    float cz = fminf(fmaxf(wz, mnz), mxz);
    float ddx = wx - cx, ddy = wy - cy, ddz = wz - cz;
    float bd2 = ddx * ddx + ddy * ddy + ddz * ddz;
    const bool fire = (bd2 * 0.999f < lg * lg);
    if (fire) {
#pragma unroll
      for (int j = 0; j < PPT; ++j)
        dd[j] = fminf(dd[j], sqrtf(eucl2(x[j], y[j], z[j], wx, wy, wz)));
    }

    // ---- hit waves refresh + publish; untouched waves carry forward ----
    if (__ballot((fire || own) ? 1 : 0)) {
      if (fire || own) { RESCAN(); }
      float rv = bv; int rk = bkey;
      dpp_sel2<0x111>(rv, rk); dpp_sel2<0x112>(rv, rk); dpp_sel2<0x114>(rv, rk);
      dpp_sel2<0x118>(rv, rk); dpp_sel2<0x142>(rv, rk); dpp_sel2<0x143>(rv, rk);
      if (lane == 63) slots[pn * 16 + wave] = make_int2(__float_as_int(rv), rk);
    } else {
      if (lane == wave) slots[pn * 16 + wave] = sl;
    }
    __syncthreads();
  }

  // ---- emit selection flags to global (orig-indexed) ----
#pragma unroll
  for (int j = 0; j < PPT; ++j)
    if ((selmask >> j) & 1) selb[key[j] >> 13] = 1;
}

// ---------------------------------------------------------------------------
// Emit selected points in ascending ORIGINAL index order (block prefix sum).
// ---------------------------------------------------------------------------
__global__ __launch_bounds__(1024) void emit_kernel(const unsigned char* __restrict__ selb,
                                                    const float* __restrict__ pos,
                                                    float* __restrict__ pos_out) {
  __shared__ int sc[1024];
  const int tid = threadIdx.x;
  int w0 = ((const int*)selb)[tid * 2 + 0];
  int w1 = ((const int*)selb)[tid * 2 + 1];
  int cnt = __popc(w0) + __popc(w1);    // bytes are exactly 0 or 1
  sc[tid] = cnt;
  __syncthreads();
  for (int off = 1; off < 1024; off <<= 1) {
    int u = (tid >= off) ? sc[tid - off] : 0;
    __syncthreads();
    sc[tid] += u;
    __syncthreads();
  }
  int r = sc[tid] - cnt;
#pragma unroll
  for (int j = 0; j < 8; ++j) {
    int w = (j < 4) ? w0 : w1;
    if ((w >> ((j & 3) * 8)) & 1) {
      int oi = tid * 8 + j;
      pos_out[r * 3 + 0] = pos[oi * 3 + 0];
      pos_out[r * 3 + 1] = pos[oi * 3 + 1];
      pos_out[r * 3 + 2] = pos[oi * 3 + 2];
      ++r;
    }
  }
}

// ---------------------------------------------------------------------------
// W^T (256x256) into scratch (start of mask region; overwritten later).
// ---------------------------------------------------------------------------
__global__ __launch_bounds__(256) void wt_kernel(const float* __restrict__ W,
                                                 float* __restrict__ WT) {
  int i = blockIdx.x * 256 + threadIdx.x;
  int c = i >> 8, cp = i & 255;
  WT[i] = W[cp * 256 + c];
}

// ---------------------------------------------------------------------------
// Fused sparse aggregation + Linear. One block per node m.
// ---------------------------------------------------------------------------
__global__ __launch_bounds__(256) void agg_linear_kernel(
    const float* __restrict__ h, const float* __restrict__ pos,
    const float* __restrict__ nodepos, const float* __restrict__ WT,
    const float* __restrict__ bias, float* __restrict__ embed, float sb) {
  const int m = blockIdx.x;
  const int tid = threadIdx.x;
  const int lane = tid & 63, wave = tid >> 6;
  const float nx = nodepos[m * 3 + 0];
  const float ny = nodepos[m * 3 + 1];
  const float nz = nodepos[m * 3 + 2];
  const float4* h4 = (const float4*)h;

  float4 acc = make_float4(0.f, 0.f, 0.f, 0.f);
  const int base0 = wave * (FPS_N / 4);
  for (int base = base0; base < base0 + (FPS_N / 4); base += 64) {
    int n = base + lane;
    float px = pos[n * 3 + 0], py = pos[n * 3 + 1], pz = pos[n * 3 + 2];
    unsigned long long mb = __ballot((p3sum(px, py, pz, nx, ny, nz) <= sb) ? 1 : 0);
    while (mb) {
      int b = __ffsll(mb) - 1;
      mb &= (mb - 1);
      float4 hv = h4[(size_t)(base + b) * 64 + lane];
      acc.x += hv.x; acc.y += hv.y; acc.z += hv.z; acc.w += hv.w;
    }
  }

  __shared__ float lacc[4][256];
  lacc[wave][lane * 4 + 0] = acc.x;
  lacc[wave][lane * 4 + 1] = acc.y;
  lacc[wave][lane * 4 + 2] = acc.z;
  lacc[wave][lane * 4 + 3] = acc.w;
  __syncthreads();
  __shared__ float aggrow[256];
  float aggv = ((lacc[0][tid] + lacc[1][tid]) + lacc[2][tid]) + lacc[3][tid];
  aggrow[tid] = aggv;
  __syncthreads();

  float o = bias[tid];
#pragma unroll 8
  for (int c = 0; c < 256; ++c)
    o = fmaf(aggrow[c], WT[c * 256 + tid], o);
  embed[(size_t)m * 256 + tid] = o;
}

// ---------------------------------------------------------------------------
// Mask output: mask[n][m] = (sum|d|^3 <= sb) ? 1.0 : 0.0   (8192 x 4096 f32)
// ---------------------------------------------------------------------------
__global__ __launch_bounds__(256) void mask_kernel(const float* __restrict__ pos,
                                                   const float* __restrict__ nodepos,
                                                   float* __restrict__ maskout,
                                                   float sb) {
  int n  = blockIdx.y;
  int m0 = (blockIdx.x * 256 + threadIdx.x) * 4;
  float x = pos[n * 3 + 0], y = pos[n * 3 + 1], z = pos[n * 3 + 2];
  const float4* np4 = (const float4*)(nodepos + (size_t)m0 * 3);
  float4 a = np4[0], bq = np4[1], cq = np4[2];
  float4 r;
  r.x = (p3sum(x, y, z, a.x,  a.y,  a.z)  <= sb) ? 1.0f : 0.0f;
  r.y = (p3sum(x, y, z, a.w,  bq.x, bq.y) <= sb) ? 1.0f : 0.0f;
  r.z = (p3sum(x, y, z, bq.z, bq.w, cq.x) <= sb) ? 1.0f : 0.0f;
  r.w = (p3sum(x, y, z, cq.y, cq.z, cq.w) <= sb) ? 1.0f : 0.0f;
  *(float4*)(maskout + (size_t)n * FPS_K + m0) = r;
}

extern "C" void kernel_launch(void* const* d_in, const int* in_sizes, int n_in,
                              void* d_out, int out_size, void* d_ws, size_t ws_size,
                              hipStream_t stream) {
  (void)in_sizes; (void)n_in; (void)out_size; (void)d_ws; (void)ws_size;
  const float* h   = (const float*)d_in[0];
  const float* pos = (const float*)d_in[1];
  const float* W   = (const float*)d_in[2];
  const float* b   = (const float*)d_in[3];

  float* out     = (float*)d_out;
  float* embed   = out;                                   // 4096*256
  float* pos_out = out + (size_t)FPS_K * CS;              // 4096*3
  float* mask    = pos_out + (size_t)FPS_K * 3;           // 8192*4096
  float* WT      = mask;                                  // scratch (overwritten)
  float* px      = mask + (1 << 21);                      // sorted SoA scratch
  float* py      = px + FPS_N;
  float* pz      = py + FPS_N;
  unsigned short* ids16 = (unsigned short*)(pz + FPS_N);
  unsigned char*  selb  = ((unsigned char*)ids16) + 2 * FPS_N;

  // Threshold model: ref mask true  <=>  cbrt_f32(s) < 0.3f
  const float  t    = 0.3f;
  const float  ulpv = nextafterf(t, 1.0f) - t;
  const double rmid = (double)t - (double)ulpv * 0.5;
  const double C    = rmid * rmid * rmid;
  float sb = (float)C;
  if (!((double)sb < C)) sb = nextafterf(sb, 0.0f);

  hipFuncSetAttribute((const void*)fps_kernel,
                      hipFuncAttributeMaxDynamicSharedMemorySize, FPS_LDS_BYTES);

  hipLaunchKernelGGL(bin_kernel, dim3(1), dim3(1024), 0, stream,
                     pos, px, py, pz, ids16, selb);
  hipLaunchKernelGGL(fps_kernel, dim3(1), dim3(FT), FPS_LDS_BYTES, stream,
                     pos, px, py, pz, ids16, selb);
  hipLaunchKernelGGL(emit_kernel, dim3(1), dim3(1024), 0, stream,
                     selb, pos, pos_out);
  hipLaunchKernelGGL(wt_kernel, dim3(256), dim3(256), 0, stream, W, WT);
  hipLaunchKernelGGL(agg_linear_kernel, dim3(FPS_K), dim3(256), 0, stream,
                     h, pos, pos_out, WT, b, embed, sb);
  hipLaunchKernelGGL(mask_kernel, dim3(4, FPS_N), dim3(256), 0, stream,
                     pos, pos_out, mask, sb);
}